// Round 3
// baseline (437.468 us; speedup 1.0000x reference)
//
#include <hip/hip_runtime.h>

// TopKRouter: N=32768 tokens, D=2048, E=64, K=2.
// R3: scalar-broadcast GEMM, 8-wave blocks (8 experts/wave), KB=64 chunks,
// double-buffered LDS x-stage (1 barrier/chunk), e-inner FMA ILP.

#define NTOK 32768
#define DDIM 2048
#define NEXP 64
#define TTILE 64          // tokens per block
#define KB 64             // k-chunk
#define NCH (DDIM / KB)   // 32
#define XS_STRIDE 68      // 64 + 4 pad, rows stay 16B-aligned

#define OFF_IDX 0
#define OFF_W 65536
#define OFF_CNT 131072
#define OFF_OVF 131136
#define OFF_ZL 131137
#define OFF_ENT 131138
#define OFF_VAR 131139
#define OFF_CONF 131140

struct RouterWS {
  unsigned int counts[NEXP];
  double z_sum;
  double ent_sum;
};

__global__ __launch_bounds__(512, 4) void router_main(
    const float* __restrict__ x, const float* __restrict__ w,
    float* __restrict__ out, RouterWS* __restrict__ ws) {
  // Two x-stage buffers; buffer 0 is reused as the logit tile for the tail.
  __shared__ float smem[2 * TTILE * XS_STRIDE];
  __shared__ unsigned int hist[NEXP];

  const int tid = threadIdx.x;
  const int lane = tid & 63;                                // token-in-block
  const int wv = __builtin_amdgcn_readfirstlane(tid >> 6);  // expert group 0..7

  const float* xg = x + (size_t)blockIdx.x * TTILE * DDIM;

  // staging map: 1024 float4 per chunk, 2 per thread, same row
  const int row = tid >> 3;          // 0..63
  const int c40 = (tid & 7) * 4;     // float col 0..28

  float4 rx0 = *(const float4*)(xg + (size_t)row * DDIM + c40);
  float4 rx1 = *(const float4*)(xg + (size_t)row * DDIM + c40 + 32);
  *(float4*)&smem[row * XS_STRIDE + c40] = rx0;
  *(float4*)&smem[row * XS_STRIDE + c40 + 32] = rx1;

  float acc[8];
#pragma unroll
  for (int e = 0; e < 8; ++e) acc[e] = 0.f;

  const float* wbase = w + (size_t)wv * 8 * DDIM;
  __syncthreads();

  for (int c = 0; c < NCH; ++c) {
    float* cur = &smem[(c & 1) * TTILE * XS_STRIDE];
    float* nxt = &smem[((c + 1) & 1) * TTILE * XS_STRIDE];

    if (c + 1 < NCH) {  // issue next-chunk loads; latency hides under FMAs
      int k0 = (c + 1) * KB;
      rx0 = *(const float4*)(xg + (size_t)row * DDIM + k0 + c40);
      rx1 = *(const float4*)(xg + (size_t)row * DDIM + k0 + c40 + 32);
    }

    // my token's 64 x-values -> VGPRs (16 ds_read_b128, reused by 8 experts)
    float xr[KB];
#pragma unroll
    for (int m = 0; m < 16; ++m)
      *(float4*)&xr[4 * m] = *(const float4*)&cur[lane * XS_STRIDE + 4 * m];

    const float* wc = wbase + c * KB;
#pragma unroll
    for (int m = 0; m < 16; ++m) {
      float4 xq = *(const float4*)&xr[4 * m];
#pragma unroll
      for (int e = 0; e < 8; ++e) {  // 8 independent chains between dep FMAs
        float4 wq = ((const float4*)(wc + (size_t)e * DDIM))[m];  // s_load
        float a = acc[e];
        a = fmaf(xq.x, wq.x, a);
        a = fmaf(xq.y, wq.y, a);
        a = fmaf(xq.z, wq.z, a);
        a = fmaf(xq.w, wq.w, a);
        acc[e] = a;
      }
    }

    if (c + 1 < NCH) {  // loads long since returned; stage next buffer
      *(float4*)&nxt[row * XS_STRIDE + c40] = rx0;
      *(float4*)&nxt[row * XS_STRIDE + c40 + 32] = rx1;
    }
    __syncthreads();
  }

  // logits -> smem buffer 0 as lg[token][expert], stride 68
#pragma unroll
  for (int m = 0; m < 2; ++m)
    *(float4*)&smem[lane * XS_STRIDE + wv * 8 + 4 * m] = *(float4*)&acc[4 * m];
  if (tid < NEXP) hist[tid] = 0;
  __syncthreads();

  if (tid < NEXP) {  // wave 0: one token per lane, serial over 64 experts
    const int t = tid;
    const float* L = &smem[t * XS_STRIDE];

    float m1 = L[0];
    int i1 = 0;
    for (int e = 1; e < NEXP; ++e) {
      float v = L[e];
      if (v > m1) { m1 = v; i1 = e; }  // strict > keeps lowest index on ties
    }
    float m2 = -3.4e38f;
    int i2 = 0;
    for (int e = 0; e < NEXP; ++e) {
      if (e == i1) continue;
      float v = L[e];
      if (v > m2) { m2 = v; i2 = e; }
    }

    float s = 0.f;
    for (int e = 0; e < NEXP; ++e) s += expf(L[e] - m1);
    float p1 = expf(L[i1] - m1) / s;
    float p2 = expf(L[i2] - m1) / s;
    float wsum = p1 + p2 + 1e-8f;
    float w1 = p1 / wsum;
    float w2 = p2 / wsum;

    float ent = 0.f;
    for (int e = 0; e < NEXP; ++e) {
      float p = expf(L[e] - m1) / s;
      ent -= p * logf(p + 1e-10f);
    }
    float lse = m1 + logf(s);

    size_t gt = (size_t)blockIdx.x * TTILE + t;
    out[OFF_IDX + gt * 2 + 0] = (float)i1;
    out[OFF_IDX + gt * 2 + 1] = (float)i2;
    out[OFF_W + gt * 2 + 0] = w1;
    out[OFF_W + gt * 2 + 1] = w2;
    out[OFF_CONF + gt] = fmaxf(w1, w2);

    atomicAdd(&hist[i1], 1u);
    atomicAdd(&hist[i2], 1u);

    float zv = lse, ev = ent;
#pragma unroll
    for (int o = 32; o > 0; o >>= 1) {
      zv += __shfl_down(zv, o);
      ev += __shfl_down(ev, o);
    }
    if (t == 0) {
      atomicAdd(&ws->z_sum, (double)zv);
      atomicAdd(&ws->ent_sum, (double)ev);
    }
  }
  __syncthreads();
  if (tid < NEXP) atomicAdd(&ws->counts[tid], hist[tid]);
}

__global__ void router_final(float* __restrict__ out, RouterWS* __restrict__ ws) {
  int e = threadIdx.x;  // 64 threads
  float c = (float)ws->counts[e];
  out[OFF_CNT + e] = c;
  float over = fmaxf(c - 1280.f, 0.f);   // capacity = int(1.25*32768/64*2)
  float ld = c / 65536.f - (1.f / 64.f);
  float so = over, sv = ld * ld;
#pragma unroll
  for (int o = 32; o > 0; o >>= 1) {
    so += __shfl_down(so, o);
    sv += __shfl_down(sv, o);
  }
  if (e == 0) {
    out[OFF_OVF] = so / 32768.f * 100.f;
    out[OFF_VAR] = sv / 64.f;
    out[OFF_ZL] = (float)(ws->z_sum / 32768.0 * 0.01);
    out[OFF_ENT] = (float)(ws->ent_sum / 32768.0);
  }
}

extern "C" void kernel_launch(void* const* d_in, const int* in_sizes, int n_in,
                              void* d_out, int out_size, void* d_ws, size_t ws_size,
                              hipStream_t stream) {
  const float* x = (const float*)d_in[0];   // hidden_states [4,8192,2048] f32
  const float* w = (const float*)d_in[1];   // gate_weight [64,2048] f32
  float* out = (float*)d_out;
  RouterWS* ws = (RouterWS*)d_ws;

  hipMemsetAsync(d_ws, 0, sizeof(RouterWS), stream);
  hipLaunchKernelGGL(router_main, dim3(NTOK / TTILE), dim3(512), 0, stream,
                     x, w, out, ws);
  hipLaunchKernelGGL(router_final, dim3(1), dim3(64), 0, stream, out, ws);
}

// Round 5
// 263.817 us; speedup vs baseline: 1.6582x; 1.6582x over previous
//
#include <hip/hip_runtime.h>

// TopKRouter: N=32768 tokens, D=2048, E=64, K=2.
// R5 = R4 with the addrspace fix: no LDS pointer arrays; buffer selection is
// offset arithmetic. w staged to LDS (uniform-address broadcast ds_read_b128),
// 8-wave blocks, R2's proven e-outer/m-inner KB=32 FMA shape.

#define NTOK 32768
#define DDIM 2048
#define NEXP 64
#define TTILE 64          // tokens per block
#define KB 32             // k-chunk
#define NCH (DDIM / KB)   // 64
#define XS_STRIDE 36      // 32 + 4 pad
#define LG_STRIDE 68      // 64 + 4 pad for logit tail
#define BUFSZ (TTILE * XS_STRIDE)

#define OFF_IDX 0
#define OFF_W 65536
#define OFF_CNT 131072
#define OFF_OVF 131136
#define OFF_ZL 131137
#define OFF_ENT 131138
#define OFF_VAR 131139
#define OFF_CONF 131140

struct RouterWS {
  unsigned int counts[NEXP];
  double z_sum;
  double ent_sum;
};

__global__ __launch_bounds__(512, 4) void router_main(
    const float* __restrict__ x, const float* __restrict__ w,
    float* __restrict__ out, RouterWS* __restrict__ ws) {
  // layout: [0,BUFSZ) x buf0 | [BUFSZ,2B) x buf1 | [2B,3B) w buf0 | [3B,4B) w buf1
  // Logit tile (64*68 floats) aliases the front after the last barrier.
  __shared__ float smem[4 * BUFSZ];
  __shared__ unsigned int hist[NEXP];

  const int tid = threadIdx.x;                              // 0..511
  const int lane = tid & 63;                                // token-in-block
  const int wv = __builtin_amdgcn_readfirstlane(tid >> 6);  // expert group 0..7

  const float* xg = x + (size_t)blockIdx.x * TTILE * DDIM;

  // staging map (x and w identical): row = tid>>3 (0..63), col = (tid&7)*4
  const int srow = tid >> 3;
  const int scol = (tid & 7) * 4;

  // Prefetch chunk 0.
  float4 rx = *(const float4*)(xg + (size_t)srow * DDIM + scol);
  float4 rw = *(const float4*)(w + (size_t)srow * DDIM + scol);
  *(float4*)&smem[0 * BUFSZ + srow * XS_STRIDE + scol] = rx;
  *(float4*)&smem[2 * BUFSZ + srow * XS_STRIDE + scol] = rw;

  float acc[8];
#pragma unroll
  for (int e = 0; e < 8; ++e) acc[e] = 0.f;

  __syncthreads();

  for (int c = 0; c < NCH; ++c) {
    const int cb = (c & 1) * BUFSZ;       // current buffer offset
    const int nb = ((c + 1) & 1) * BUFSZ; // next buffer offset

    if (c + 1 < NCH) {  // issue next-chunk global loads; return under FMAs
      int k0 = (c + 1) * KB;
      rx = *(const float4*)(xg + (size_t)srow * DDIM + k0 + scol);
      rw = *(const float4*)(w + (size_t)srow * DDIM + k0 + scol);
    }

    // my token's 32 x-values -> VGPRs (8 ds_read_b128, reused by 8 experts)
    float4 xr4[8];
#pragma unroll
    for (int m = 0; m < 8; ++m)
      xr4[m] = *(const float4*)&smem[cb + lane * XS_STRIDE + 4 * m];

#pragma unroll
    for (int e = 0; e < 8; ++e) {
      // uniform address across the wave -> LDS broadcast, no conflicts
      const float* wrow = &smem[2 * BUFSZ + cb + (8 * wv + e) * XS_STRIDE];
      float a = acc[e];
#pragma unroll
      for (int m = 0; m < 8; ++m) {
        float4 wq = *(const float4*)&wrow[4 * m];
        a = fmaf(xr4[m].x, wq.x, a);
        a = fmaf(xr4[m].y, wq.y, a);
        a = fmaf(xr4[m].z, wq.z, a);
        a = fmaf(xr4[m].w, wq.w, a);
      }
      acc[e] = a;
    }

    if (c + 1 < NCH) {  // loads returned by now; stage next buffers
      *(float4*)&smem[nb + srow * XS_STRIDE + scol] = rx;
      *(float4*)&smem[2 * BUFSZ + nb + srow * XS_STRIDE + scol] = rw;
    }
    __syncthreads();
  }

  // logits -> smem front as lg[token][expert], stride 68
#pragma unroll
  for (int m = 0; m < 2; ++m)
    *(float4*)&smem[lane * LG_STRIDE + wv * 8 + 4 * m] = *(float4*)&acc[4 * m];
  if (tid < NEXP) hist[tid] = 0;
  __syncthreads();

  if (tid < NEXP) {  // wave 0: one token per lane, serial over 64 experts
    const int t = tid;
    const float* L = &smem[t * LG_STRIDE];

    float m1 = L[0];
    int i1 = 0;
    for (int e = 1; e < NEXP; ++e) {
      float v = L[e];
      if (v > m1) { m1 = v; i1 = e; }  // strict > keeps lowest index on ties
    }
    float m2 = -3.4e38f;
    int i2 = 0;
    for (int e = 0; e < NEXP; ++e) {
      if (e == i1) continue;
      float v = L[e];
      if (v > m2) { m2 = v; i2 = e; }
    }

    float s = 0.f;
    for (int e = 0; e < NEXP; ++e) s += expf(L[e] - m1);
    float p1 = expf(L[i1] - m1) / s;
    float p2 = expf(L[i2] - m1) / s;
    float wsum = p1 + p2 + 1e-8f;
    float w1 = p1 / wsum;
    float w2 = p2 / wsum;

    float ent = 0.f;
    for (int e = 0; e < NEXP; ++e) {
      float p = expf(L[e] - m1) / s;
      ent -= p * logf(p + 1e-10f);
    }
    float lse = m1 + logf(s);

    size_t gt = (size_t)blockIdx.x * TTILE + t;
    out[OFF_IDX + gt * 2 + 0] = (float)i1;
    out[OFF_IDX + gt * 2 + 1] = (float)i2;
    out[OFF_W + gt * 2 + 0] = w1;
    out[OFF_W + gt * 2 + 1] = w2;
    out[OFF_CONF + gt] = fmaxf(w1, w2);

    atomicAdd(&hist[i1], 1u);
    atomicAdd(&hist[i2], 1u);

    float zv = lse, ev = ent;
#pragma unroll
    for (int o = 32; o > 0; o >>= 1) {
      zv += __shfl_down(zv, o);
      ev += __shfl_down(ev, o);
    }
    if (t == 0) {
      atomicAdd(&ws->z_sum, (double)zv);
      atomicAdd(&ws->ent_sum, (double)ev);
    }
  }
  __syncthreads();
  if (tid < NEXP) atomicAdd(&ws->counts[tid], hist[tid]);
}

__global__ void router_final(float* __restrict__ out, RouterWS* __restrict__ ws) {
  int e = threadIdx.x;  // 64 threads
  float c = (float)ws->counts[e];
  out[OFF_CNT + e] = c;
  float over = fmaxf(c - 1280.f, 0.f);   // capacity = int(1.25*32768/64*2)
  float ld = c / 65536.f - (1.f / 64.f);
  float so = over, sv = ld * ld;
#pragma unroll
  for (int o = 32; o > 0; o >>= 1) {
    so += __shfl_down(so, o);
    sv += __shfl_down(sv, o);
  }
  if (e == 0) {
    out[OFF_OVF] = so / 32768.f * 100.f;
    out[OFF_VAR] = sv / 64.f;
    out[OFF_ZL] = (float)(ws->z_sum / 32768.0 * 0.01);
    out[OFF_ENT] = (float)(ws->ent_sum / 32768.0);
  }
}

extern "C" void kernel_launch(void* const* d_in, const int* in_sizes, int n_in,
                              void* d_out, int out_size, void* d_ws, size_t ws_size,
                              hipStream_t stream) {
  const float* x = (const float*)d_in[0];   // hidden_states [4,8192,2048] f32
  const float* w = (const float*)d_in[1];   // gate_weight [64,2048] f32
  float* out = (float*)d_out;
  RouterWS* ws = (RouterWS*)d_ws;

  (void)hipMemsetAsync(d_ws, 0, sizeof(RouterWS), stream);
  hipLaunchKernelGGL(router_main, dim3(NTOK / TTILE), dim3(512), 0, stream,
                     x, w, out, ws);
  hipLaunchKernelGGL(router_final, dim3(1), dim3(64), 0, stream, out, ws);
}